// Round 8
// baseline (185.149 us; speedup 1.0000x reference)
//
#include <hip/hip_runtime.h>
#include <math.h>

#define BS   8192
#define DD   768
#define NC   64
#define NCL  500
#define CS   100
#define NY   1000
#define EPSN 1e-12f

#define NBT 256    // tmat: 64 row-tiles(128) x 4 k-splits(192)
#define NBG 64     // gram
#define NBU 32     // U: 8 n-tiles(128) x 4 k-splits(192)

#define FMA4(acc, s, v) { (acc).x = fmaf((s), (v).x, (acc).x); \
                          (acc).y = fmaf((s), (v).y, (acc).y); \
                          (acc).z = fmaf((s), (v).z, (acc).z); \
                          (acc).w = fmaf((s), (v).w, (acc).w); }

// ============ K1: tmat(ksplit) || gram || U(ksplit) ============
__global__ __launch_bounds__(256) void k_gemms(
    const float* __restrict__ C, const float* __restrict__ W,
    const float* __restrict__ X, float* __restrict__ gram,
    float* __restrict__ Up, float* __restrict__ Tp) {
    __shared__ __align__(16) char smem_raw[52224];
    int b = blockIdx.x, tid = threadIdx.x;

    if (b < NBT) {
        // T-partial = X[128 rows][192-k slice] @ C. Row-major LDS (no transpose):
        // staging is pure float4 writes; inner reads are b128 broadcasts.
        int tile = b >> 2, ks = b & 3;
        int r0 = tile * 128, kb = ks * 192;
        float (*Xr)[68] = (float(*)[68])smem_raw;                 // [128][68]
        float (*Cs)[68] = (float(*)[68])(smem_raw + 128*68*4);    // [64][68]
        int tx = tid & 15, ty = tid >> 4;      // cols tx*4..+3, rows ty*8..+7
        float4 acc[8];
        #pragma unroll
        for (int r = 0; r < 8; ++r) acc[r] = make_float4(0.f,0.f,0.f,0.f);
        for (int kc = 0; kc < 192; kc += 64) {
            __syncthreads();
            #pragma unroll
            for (int p = 0; p < 8; ++p) {      // stage X rows: 128x64
                int f = tid + p * 256;
                int row = f >> 4, k4 = f & 15;
                *((float4*)&Xr[row][k4*4]) =
                    *((const float4*)(X + (size_t)(r0+row)*DD + kb+kc + k4*4));
            }
            #pragma unroll
            for (int p = 0; p < 4; ++p) {      // stage C: 64x64
                int f = tid + p * 256;
                int k = f >> 4, c4 = f & 15;
                *((float4*)&Cs[k][c4*4]) =
                    *((const float4*)(C + (size_t)(kb+kc+k)*64 + c4*4));
            }
            __syncthreads();
            for (int k0 = 0; k0 < 64; k0 += 4) {
                float4 cv0 = *((float4*)&Cs[k0+0][tx*4]);
                float4 cv1 = *((float4*)&Cs[k0+1][tx*4]);
                float4 cv2 = *((float4*)&Cs[k0+2][tx*4]);
                float4 cv3 = *((float4*)&Cs[k0+3][tx*4]);
                #pragma unroll
                for (int r = 0; r < 8; ++r) {
                    float4 xv = *((float4*)&Xr[ty*8+r][k0]);
                    FMA4(acc[r], xv.x, cv0);
                    FMA4(acc[r], xv.y, cv1);
                    FMA4(acc[r], xv.z, cv2);
                    FMA4(acc[r], xv.w, cv3);
                }
            }
        }
        float* Tps = Tp + (size_t)ks * BS * 64;
        #pragma unroll
        for (int r = 0; r < 8; ++r)
            *((float4*)(Tps + (size_t)(r0 + ty*8 + r)*64 + tx*4)) = acc[r];
    } else if (b < NBT + NBG) {
        // gram = C^T C
        int j   = b - NBT;
        int i   = tid & 63;
        int seg = tid >> 6;
        float p = 0.f;
        for (int k = seg * 192; k < seg * 192 + 192; ++k)
            p += C[k * NC + i] * C[k * NC + j];
        float (*red)[64] = (float(*)[64])smem_raw;
        red[seg][i] = p;
        __syncthreads();
        if (seg == 0)
            gram[i * NC + j] = red[0][i] + red[1][i] + red[2][i] + red[3][i];
    } else {
        // U-partial = C^T[kslice] @ W[kslice][128 cols] (R7 body, already fine)
        int q  = b - (NBT + NBG);
        int nt = q >> 2, ks = q & 3;
        int n0 = nt * 128, kb = ks * 192;
        float (*Cu)[68]  = (float(*)[68])smem_raw;                // [32][68]
        float (*Wu)[132] = (float(*)[132])(smem_raw + 8704);      // [32][132]
        int tx = tid & 15, ty = tid >> 4;
        float4 a0[4], a1[4];
        #pragma unroll
        for (int i = 0; i < 4; ++i) { a0[i] = make_float4(0,0,0,0); a1[i] = make_float4(0,0,0,0); }
        for (int kc = kb; kc < kb + 192; kc += 32) {
            __syncthreads();
            {   int i4 = tid & 15, kk = tid >> 4;
                *((float4*)&Cu[kk][i4*4])    = *((const float4*)(C + (size_t)(kc+kk)*64 + i4*4));
                *((float4*)&Cu[kk+16][i4*4]) = *((const float4*)(C + (size_t)(kc+kk+16)*64 + i4*4));
            }
            {   int nf = tid & 31, kq = tid >> 5;
                #pragma unroll
                for (int u = 0; u < 4; ++u) {
                    int k = kq + u * 8;
                    int n = n0 + nf * 4;
                    float4 v = {0.f, 0.f, 0.f, 0.f};
                    if (n < NY) v = *((const float4*)(W + (size_t)(kc + k) * NY + n));
                    *((float4*)&Wu[k][nf*4]) = v;
                }
            }
            __syncthreads();
            #pragma unroll 8
            for (int k = 0; k < 32; ++k) {
                float4 ci = *((float4*)&Cu[k][ty*4]);
                float4 w0 = *((float4*)&Wu[k][tx*8]);
                float4 w1 = *((float4*)&Wu[k][tx*8+4]);
                FMA4(a0[0], ci.x, w0); FMA4(a1[0], ci.x, w1);
                FMA4(a0[1], ci.y, w0); FMA4(a1[1], ci.y, w1);
                FMA4(a0[2], ci.z, w0); FMA4(a1[2], ci.z, w1);
                FMA4(a0[3], ci.w, w0); FMA4(a1[3], ci.w, w1);
            }
        }
        float* Ups = Up + (size_t)ks * 64000;
        #pragma unroll
        for (int i = 0; i < 4; ++i) {
            int irow = ty * 4 + i;
            int n = n0 + tx * 8;
            if (n < NY)     *((float4*)(Ups + (size_t)irow * NY + n))     = a0[i];
            if (n + 4 < NY) *((float4*)(Ups + (size_t)irow * NY + n + 4)) = a1[i];
        }
    }
}

// ============ K2: cluster_mean (isolated for per-role profiling) ============
__global__ __launch_bounds__(256) void k_cmean(const float* __restrict__ clusters,
                                               float* __restrict__ cm) {
    int idx = blockIdx.x * 256 + threadIdx.x;
    int r  = idx / (DD / 4);
    int d4 = idx % (DD / 4);
    const float4* base = (const float4*)(clusters + (size_t)r * CS * DD) + d4;
    float4 a0 = {0,0,0,0}, a1 = {0,0,0,0}, a2 = {0,0,0,0}, a3 = {0,0,0,0};
    for (int s = 0; s < CS; s += 4) {
        float4 v0 = base[(size_t)(s + 0) * (DD / 4)];
        float4 v1 = base[(size_t)(s + 1) * (DD / 4)];
        float4 v2 = base[(size_t)(s + 2) * (DD / 4)];
        float4 v3 = base[(size_t)(s + 3) * (DD / 4)];
        a0.x += v0.x; a0.y += v0.y; a0.z += v0.z; a0.w += v0.w;
        a1.x += v1.x; a1.y += v1.y; a1.z += v1.z; a1.w += v1.w;
        a2.x += v2.x; a2.y += v2.y; a2.z += v2.z; a2.w += v2.w;
        a3.x += v3.x; a3.y += v3.y; a3.z += v3.z; a3.w += v3.w;
    }
    float4 o;
    const float sc = 1.0f / CS;
    o.x = (a0.x + a1.x + a2.x + a3.x) * sc;
    o.y = (a0.y + a1.y + a2.y + a3.y) * sc;
    o.z = (a0.z + a1.z + a2.z + a3.z) * sc;
    o.w = (a0.w + a1.w + a2.w + a3.w) * sc;
    ((float4*)cm)[idx] = o;
}

// ============ K3: inv (block 0) || score partials (blocks 1..16) ============
__global__ __launch_bounds__(256) void k_phaseB(
    const float* __restrict__ gram, const float* __restrict__ cm,
    const float* __restrict__ C, float* __restrict__ ginv,
    float* __restrict__ SP) {
    __shared__ __align__(16) char smem_raw[52224];
    int blk = blockIdx.x;
    int tid = threadIdx.x;
    if (blk == 0) {
        // register-resident Gauss-Jordan (verified R3 body)
        int c = tid & 63;
        int q = tid >> 6;
        float a[16], bb[16];
        #pragma unroll
        for (int i = 0; i < 16; ++i) {
            int r = q * 16 + i;
            a[i]  = gram[r * 64 + c];
            bb[i] = (r == c) ? 1.f : 0.f;
        }
        __shared__ float asr[2][64];
        __shared__ float bsr[2][64];
        for (int p = 0; p < 64; ++p) {
            int qp  = p >> 4;
            int lp  = p & 15;
            int par = p & 1;
            if (q == qp) {
                float ap = 0.f, bp = 0.f;
                #pragma unroll
                for (int i = 0; i < 16; ++i)
                    if (i == lp) { ap = a[i]; bp = bb[i]; }
                float App = __shfl(ap, p);
                float s   = 1.0f / App;
                asr[par][c] = ap * s;
                bsr[par][c] = bp * s;
            }
            __syncthreads();
            float as_ = asr[par][c];
            float bs_ = bsr[par][c];
            #pragma unroll
            for (int i = 0; i < 16; ++i) {
                float f = __shfl(a[i], p);
                bool isp = (q == qp) && (i == lp);
                a[i]  = isp ? as_ : fmaf(-f, as_, a[i]);
                bb[i] = isp ? bs_ : fmaf(-f, bs_, bb[i]);
            }
        }
        #pragma unroll
        for (int i = 0; i < 16; ++i)
            ginv[(q * 16 + i) * 64 + c] = bb[i];
    } else {
        // SP-partial = cm[128 rows][192-k slice] @ C (raw; abs after summing)
        int q = blk - 1;
        int tile = q >> 2, ks = q & 3;
        int r0 = tile * 128, kb = ks * 192;
        float (*Mr)[68] = (float(*)[68])smem_raw;                 // [128][68]
        float (*Cs)[68] = (float(*)[68])(smem_raw + 128*68*4);    // [64][68]
        int tx = tid & 15, ty = tid >> 4;
        float4 acc[8];
        #pragma unroll
        for (int r = 0; r < 8; ++r) acc[r] = make_float4(0.f,0.f,0.f,0.f);
        for (int kc = 0; kc < 192; kc += 64) {
            __syncthreads();
            #pragma unroll
            for (int p = 0; p < 8; ++p) {
                int f = tid + p * 256;
                int row = f >> 4, k4 = f & 15;
                int gr = r0 + row;
                int grc = gr < NCL ? gr : (NCL - 1);
                *((float4*)&Mr[row][k4*4]) =
                    *((const float4*)(cm + (size_t)grc*DD + kb+kc + k4*4));
            }
            #pragma unroll
            for (int p = 0; p < 4; ++p) {
                int f = tid + p * 256;
                int k = f >> 4, c4 = f & 15;
                *((float4*)&Cs[k][c4*4]) =
                    *((const float4*)(C + (size_t)(kb+kc+k)*64 + c4*4));
            }
            __syncthreads();
            for (int k0 = 0; k0 < 64; k0 += 4) {
                float4 cv0 = *((float4*)&Cs[k0+0][tx*4]);
                float4 cv1 = *((float4*)&Cs[k0+1][tx*4]);
                float4 cv2 = *((float4*)&Cs[k0+2][tx*4]);
                float4 cv3 = *((float4*)&Cs[k0+3][tx*4]);
                #pragma unroll
                for (int r = 0; r < 8; ++r) {
                    float4 xv = *((float4*)&Mr[ty*8+r][k0]);
                    FMA4(acc[r], xv.x, cv0);
                    FMA4(acc[r], xv.y, cv1);
                    FMA4(acc[r], xv.z, cv2);
                    FMA4(acc[r], xv.w, cv3);
                }
            }
        }
        float* SPs = SP + (size_t)ks * 32000;
        #pragma unroll
        for (int r = 0; r < 8; ++r) {
            int row = r0 + ty * 8 + r;
            if (row < NCL)
                *((float4*)(SPs + (size_t)row * 64 + tx*4)) = acc[r];
        }
    }
}

// ====== K4: V = Ginv @ (sum Up), 64-col tiles (blocks 0..15) || sparse (16) ======
__global__ __launch_bounds__(256) void k_vc(
    const float* __restrict__ ginv, const float* __restrict__ Up,
    float* __restrict__ SP, float* __restrict__ V, float* __restrict__ out2) {
    __shared__ __align__(16) char smem_raw[34816];
    int blk = blockIdx.x, tid = threadIdx.x;
    if (blk == 16) {
        // sparse losses: sum 4 SP partials -> abs -> colnorm -> L1/L2
        __shared__ float colred[4][64];
        __shared__ float rn[64];
        __shared__ float trc[64];
        __shared__ float r1[4], r2[4];
        const float* SP0 = SP;
        const float* SP1 = SP + 32000;
        const float* SP2 = SP + 64000;
        const float* SP3 = SP + 96000;
        int c = tid & 63, seg = tid >> 6;
        float p = 0.f;
        for (int r = seg; r < NCL; r += 4) {
            int off = r * 64 + c;
            float s = fabsf(SP0[off] + SP1[off] + SP2[off] + SP3[off]);
            SP[off] = s;
            p += s * s;
        }
        colred[seg][c] = p;
        __syncthreads();
        if (seg == 0) {
            float n2  = colred[0][c] + colred[1][c] + colred[2][c] + colred[3][c];
            float inv = 1.0f / fmaxf(sqrtf(n2), EPSN);
            rn[c]  = inv;
            trc[c] = n2 * inv * inv;
        }
        __syncthreads();
        float l1p = 0.f, l2p = 0.f;
        for (int r = tid; r < NCL; r += 256) {
            float rs = 0.f;
            #pragma unroll
            for (int cc = 0; cc < 64; ++cc)
                rs += SP[r * 64 + cc] * rn[cc];
            l1p += rs;
            l2p += rs * rs;
        }
        #pragma unroll
        for (int off = 32; off > 0; off >>= 1) {
            l1p += __shfl_down(l1p, off);
            l2p += __shfl_down(l2p, off);
        }
        int wave = tid >> 6, lane = tid & 63;
        if (lane == 0) { r1[wave] = l1p; r2[wave] = l2p; }
        __syncthreads();
        if (tid == 0) {
            float L1 = r1[0] + r1[1] + r1[2] + r1[3];
            float L2 = r2[0] + r2[1] + r2[2] + r2[3];
            float tr = 0.f;
            #pragma unroll
            for (int cc = 0; cc < 64; ++cc) tr += trc[cc];
            out2[0] = L1;
            out2[1] = L2 - tr;
        }
        return;
    }
    // V[i][n-tile] = sum_j Ginv[i][j] * Usum[j][n]. Ginv is SYMMETRIC, so
    // Gs[j][i] row-major read works for the j-reduction with i-broadcast.
    float (*Us)[68] = (float(*)[68])smem_raw;                     // [64][68] Usum[j][n]
    float (*Gs)[68] = (float(*)[68])(smem_raw + 64*68*4);         // [64][68] Ginv[j][i]
    int c0 = blk * 64;
    int tx = tid & 15, ty = tid >> 4;    // n cols tx*4, i rows ty*4
    const float* Up0 = Up;
    const float* Up1 = Up + 64000;
    const float* Up2 = Up + 128000;
    const float* Up3 = Up + 192000;
    #pragma unroll
    for (int p = 0; p < 4; ++p) {
        int f = tid + p * 256;
        int j = f >> 4, n4 = f & 15;
        int n = c0 + n4 * 4;
        float4 v = {0.f, 0.f, 0.f, 0.f};
        if (n < NY) {
            float4 u0 = *((const float4*)(Up0 + (size_t)j * NY + n));
            float4 u1 = *((const float4*)(Up1 + (size_t)j * NY + n));
            float4 u2 = *((const float4*)(Up2 + (size_t)j * NY + n));
            float4 u3 = *((const float4*)(Up3 + (size_t)j * NY + n));
            v.x = u0.x + u1.x + u2.x + u3.x;
            v.y = u0.y + u1.y + u2.y + u3.y;
            v.z = u0.z + u1.z + u2.z + u3.z;
            v.w = u0.w + u1.w + u2.w + u3.w;
        }
        *((float4*)&Us[j][n4*4]) = v;
        *((float4*)&Gs[j][n4*4]) = *((const float4*)(ginv + (size_t)j * 64 + n4*4));
    }
    __syncthreads();
    float4 acc[4];
    #pragma unroll
    for (int i = 0; i < 4; ++i) acc[i] = make_float4(0.f,0.f,0.f,0.f);
    for (int j0 = 0; j0 < 64; j0 += 4) {
        #pragma unroll
        for (int jj = 0; jj < 4; ++jj) {
            float4 g = *((float4*)&Gs[j0+jj][ty*4]);   // Ginv[j][i..i+3] (sym)
            float4 u = *((float4*)&Us[j0+jj][tx*4]);
            FMA4(acc[0], g.x, u);
            FMA4(acc[1], g.y, u);
            FMA4(acc[2], g.z, u);
            FMA4(acc[3], g.w, u);
        }
    }
    #pragma unroll
    for (int i = 0; i < 4; ++i) {
        int n = c0 + tx * 4;
        if (n < NY)
            *((float4*)(V + (size_t)(ty*4 + i) * NY + n)) = acc[i];
    }
}

// ============ K5: y = (sum Tp) @ V + b, 128x128 tiles ============
__global__ __launch_bounds__(256) void k_ypred(
    const float* __restrict__ Tp, const float* __restrict__ V,
    const float* __restrict__ bh, float* __restrict__ Y) {
    __shared__ __align__(16) char smem_raw[68608];
    float (*Tr)[68]  = (float(*)[68])smem_raw;                    // [128][68] T[row][k]
    float (*Vs)[132] = (float(*)[132])(smem_raw + 128*68*4);      // [64][132] V[k][n]
    int blk = blockIdx.x, tid = threadIdx.x;
    int rb = blk >> 3, cb = blk & 7;
    int r0g = rb * 128, c0g = cb * 128;
    const float* Tp0 = Tp;
    const float* Tp1 = Tp + (size_t)BS * 64;
    const float* Tp2 = Tp + (size_t)BS * 128;
    const float* Tp3 = Tp + (size_t)BS * 192;
    #pragma unroll
    for (int p = 0; p < 8; ++p) {     // stage T rows (sum 4 partials), row-major
        int f = tid + p * 256;
        int row = f >> 4, k4 = f & 15;
        size_t off = (size_t)(r0g + row) * 64 + k4 * 4;
        float4 t0 = *((const float4*)(Tp0 + off));
        float4 t1 = *((const float4*)(Tp1 + off));
        float4 t2 = *((const float4*)(Tp2 + off));
        float4 t3 = *((const float4*)(Tp3 + off));
        float4 t;
        t.x = t0.x + t1.x + t2.x + t3.x;
        t.y = t0.y + t1.y + t2.y + t3.y;
        t.z = t0.z + t1.z + t2.z + t3.z;
        t.w = t0.w + t1.w + t2.w + t3.w;
        *((float4*)&Tr[row][k4*4]) = t;
    }
    #pragma unroll
    for (int p = 0; p < 8; ++p) {     // stage V tile (zero-pad n >= 1000)
        int f = tid + p * 256;
        int k = f >> 5, n8 = f & 31;
        int n = c0g + n8 * 4;
        float4 v = {0.f, 0.f, 0.f, 0.f};
        if (n < NY) v = *((const float4*)(V + (size_t)k * NY + n));
        *((float4*)&Vs[k][n8*4]) = v;
    }
    __syncthreads();
    int cx = tid & 15, ry = tid >> 4;  // cols cx*8..+7, rows ry*8..+7
    float4 lo[8], hi[8];
    #pragma unroll
    for (int r = 0; r < 8; ++r) { lo[r] = make_float4(0.f,0.f,0.f,0.f); hi[r] = lo[r]; }
    for (int k0 = 0; k0 < 64; k0 += 4) {
        float4 va0 = *((float4*)&Vs[k0+0][cx*8]), vb0 = *((float4*)&Vs[k0+0][cx*8+4]);
        float4 va1 = *((float4*)&Vs[k0+1][cx*8]), vb1 = *((float4*)&Vs[k0+1][cx*8+4]);
        float4 va2 = *((float4*)&Vs[k0+2][cx*8]), vb2 = *((float4*)&Vs[k0+2][cx*8+4]);
        float4 va3 = *((float4*)&Vs[k0+3][cx*8]), vb3 = *((float4*)&Vs[k0+3][cx*8+4]);
        #pragma unroll
        for (int r = 0; r < 8; ++r) {
            float4 tv = *((float4*)&Tr[ry*8+r][k0]);
            FMA4(lo[r], tv.x, va0); FMA4(hi[r], tv.x, vb0);
            FMA4(lo[r], tv.y, va1); FMA4(hi[r], tv.y, vb1);
            FMA4(lo[r], tv.z, va2); FMA4(hi[r], tv.z, vb2);
            FMA4(lo[r], tv.w, va3); FMA4(hi[r], tv.w, vb3);
        }
    }
    int cbase = c0g + cx * 8;
    float4 bias0 = {0,0,0,0}, bias1 = {0,0,0,0};
    if (cbase < NY)     bias0 = *((const float4*)(bh + cbase));
    if (cbase + 4 < NY) bias1 = *((const float4*)(bh + cbase + 4));
    #pragma unroll
    for (int r = 0; r < 8; ++r) {
        int row = r0g + ry * 8 + r;
        if (cbase < NY) {
            float4 o;
            o.x = lo[r].x + bias0.x; o.y = lo[r].y + bias0.y;
            o.z = lo[r].z + bias0.z; o.w = lo[r].w + bias0.w;
            *((float4*)(Y + (size_t)row * NY + cbase)) = o;
        }
        if (cbase + 4 < NY) {
            float4 o;
            o.x = hi[r].x + bias1.x; o.y = hi[r].y + bias1.y;
            o.z = hi[r].z + bias1.z; o.w = hi[r].w + bias1.w;
            *((float4*)(Y + (size_t)row * NY + cbase + 4)) = o;
        }
    }
}

extern "C" void kernel_launch(void* const* d_in, const int* in_sizes, int n_in,
                              void* d_out, int out_size, void* d_ws, size_t ws_size,
                              hipStream_t stream) {
    const float* X        = (const float*)d_in[0];   // [8192,768]
    const float* clusters = (const float*)d_in[1];   // [500,100,768]
    const float* C        = (const float*)d_in[2];   // [768,64]
    const float* W        = (const float*)d_in[3];   // [768,1000]
    const float* bh       = (const float*)d_in[4];   // [1000]
    float* out = (float*)d_out;                      // y_pred, L1, L2
    float* ws  = (float*)d_ws;

    float* cm   = ws;                   // 384000
    float* gram = cm   + 384000;        // 4096
    float* ginv = gram + 4096;          // 4096
    float* Up   = ginv + 4096;          // 4 x 64000  = 256000
    float* SP   = Up   + 256000;        // 4 x 32000  = 128000
    float* V    = SP   + 128000;        // 64000
    float* Tp   = V    + 64000;         // 4 x 524288 = 2097152

    k_gemms <<<dim3(NBT + NBG + NBU), dim3(256), 0, stream>>>(C, W, X, gram, Up, Tp);
    k_cmean <<<dim3(375), dim3(256), 0, stream>>>(clusters, cm);
    k_phaseB<<<dim3(17),  dim3(256), 0, stream>>>(gram, cm, C, ginv, SP);
    k_vc    <<<dim3(17),  dim3(256), 0, stream>>>(ginv, Up, SP, V, out + (size_t)BS * NY);
    k_ypred <<<dim3(512), dim3(256), 0, stream>>>(Tp, V, bh, out);
}

// Round 9
// 163.818 us; speedup vs baseline: 1.1302x; 1.1302x over previous
//
#include <hip/hip_runtime.h>
#include <hip/hip_bf16.h>
#include <math.h>

#define BS   8192
#define DD   768
#define NC   64
#define NCL  500
#define CS   100
#define NY   1000
#define EPSN 1e-12f

typedef __attribute__((ext_vector_type(8))) short bf16x8;
typedef __attribute__((ext_vector_type(4))) float f32x4;

union B8 { unsigned u[4]; bf16x8 v; uint4 q; };

__device__ inline unsigned short f2bf(float x) {
    __hip_bfloat16 h = __float2bfloat16(x);
    return *reinterpret_cast<unsigned short*>(&h);
}
__device__ inline unsigned pk2(float a, float b) {
    return (unsigned)f2bf(a) | ((unsigned)f2bf(b) << 16);
}

#define FMA4(acc, s, v) { (acc).x = fmaf((s), (v).x, (acc).x); \
                          (acc).y = fmaf((s), (v).y, (acc).y); \
                          (acc).z = fmaf((s), (v).z, (acc).z); \
                          (acc).w = fmaf((s), (v).w, (acc).w); }

// ============ K0: cmean s-split partials (1500) || Cb bf16 pack (24) ============
__global__ __launch_bounds__(256) void k_pre(
    const float* __restrict__ clusters, const float* __restrict__ C,
    float* __restrict__ cmP, uint4* __restrict__ Cb) {
    int b = blockIdx.x, tid = threadIdx.x;
    if (b < 1500) {
        // partial sum over 25 of the 100 cluster samples; 5 loads in flight
        int sp  = b & 3;
        int idx = (b >> 2) * 256 + tid;          // 375*256 == 500*192
        int r  = idx / 192;
        int d4 = idx % 192;
        const float4* base = (const float4*)clusters
                           + (size_t)r * CS * 192 + (size_t)sp * 25 * 192 + d4;
        float4 a0={0,0,0,0},a1={0,0,0,0},a2={0,0,0,0},a3={0,0,0,0},a4={0,0,0,0};
        for (int s = 0; s < 25; s += 5) {
            float4 v0 = base[(size_t)(s+0)*192];
            float4 v1 = base[(size_t)(s+1)*192];
            float4 v2 = base[(size_t)(s+2)*192];
            float4 v3 = base[(size_t)(s+3)*192];
            float4 v4 = base[(size_t)(s+4)*192];
            a0.x+=v0.x; a0.y+=v0.y; a0.z+=v0.z; a0.w+=v0.w;
            a1.x+=v1.x; a1.y+=v1.y; a1.z+=v1.z; a1.w+=v1.w;
            a2.x+=v2.x; a2.y+=v2.y; a2.z+=v2.z; a2.w+=v2.w;
            a3.x+=v3.x; a3.y+=v3.y; a3.z+=v3.z; a3.w+=v3.w;
            a4.x+=v4.x; a4.y+=v4.y; a4.z+=v4.z; a4.w+=v4.w;
        }
        float4 o;
        o.x = a0.x+a1.x+a2.x+a3.x+a4.x;
        o.y = a0.y+a1.y+a2.y+a3.y+a4.y;
        o.z = a0.z+a1.z+a2.z+a3.z+a4.z;
        o.w = a0.w+a1.w+a2.w+a3.w+a4.w;
        ((float4*)(cmP + (size_t)sp * 384000))[idx] = o;   // RAW sum; *0.01 at use
    } else {
        // Cb: bf16 B-fragment granules for mfma_16x16x32. granule (ks,kg,n) =
        // C[ks*32+kg*8 .. +7][n] packed as 8 bf16 (k contiguous per lane).
        int ks = b - 1500;                        // 0..23
        int kg = tid >> 6, n = tid & 63;
        const float* cp = C + (size_t)(ks*32 + kg*8) * 64 + n;
        uint4 g;
        g.x = pk2(cp[0],     cp[64]);
        g.y = pk2(cp[2*64],  cp[3*64]);
        g.z = pk2(cp[4*64],  cp[5*64]);
        g.w = pk2(cp[6*64],  cp[7*64]);
        Cb[(ks*4 + kg)*64 + n] = g;
    }
}

// ============ K1: tmat MFMA (128) || gram (64) || U f32 ksplit (32) ============
__global__ __launch_bounds__(256) void k_gemms(
    const float* __restrict__ C, const float* __restrict__ W,
    const float* __restrict__ X, const uint4* __restrict__ Cb,
    float* __restrict__ gram, float* __restrict__ Up,
    unsigned short* __restrict__ Tb) {
    __shared__ __align__(16) char smem_raw[25600];
    int b = blockIdx.x, tid = threadIdx.x;

    if (b < 128) {
        // T = X @ C via MFMA, zero LDS. Block = 64 rows (wave w: rows +w*16).
        // A-frag: lane reads X[r0+w*16+(l&15)][ks*32+(l>>4)*8 ..+7] (32B) -> bf16.
        // B-frag: Cb granule. D layout (m89): col=lane&15, row=(lane>>4)*4+reg.
        int r0 = b * 64;
        int w  = tid >> 6, l = tid & 63;
        int rowA = r0 + w*16 + (l & 15);
        int kq   = l >> 4;
        const float* xb = X + (size_t)rowA * DD + kq * 8;
        f32x4 acc[4];
        #pragma unroll
        for (int ng = 0; ng < 4; ++ng) acc[ng] = (f32x4){0.f, 0.f, 0.f, 0.f};
        #pragma unroll 2
        for (int ks = 0; ks < 24; ++ks) {
            float4 xa = *((const float4*)(xb + ks*32));
            float4 xc = *((const float4*)(xb + ks*32 + 4));
            B8 a;
            a.u[0] = pk2(xa.x, xa.y); a.u[1] = pk2(xa.z, xa.w);
            a.u[2] = pk2(xc.x, xc.y); a.u[3] = pk2(xc.z, xc.w);
            const uint4* cbase = Cb + (ks*4 + kq)*64 + (l & 15);
            B8 b0, b1, b2, b3;
            b0.q = cbase[0];  b1.q = cbase[16];
            b2.q = cbase[32]; b3.q = cbase[48];
            acc[0] = __builtin_amdgcn_mfma_f32_16x16x32_bf16(a.v, b0.v, acc[0], 0, 0, 0);
            acc[1] = __builtin_amdgcn_mfma_f32_16x16x32_bf16(a.v, b1.v, acc[1], 0, 0, 0);
            acc[2] = __builtin_amdgcn_mfma_f32_16x16x32_bf16(a.v, b2.v, acc[2], 0, 0, 0);
            acc[3] = __builtin_amdgcn_mfma_f32_16x16x32_bf16(a.v, b3.v, acc[3], 0, 0, 0);
        }
        int rw = r0 + w*16 + (l >> 4) * 4;
        #pragma unroll
        for (int ng = 0; ng < 4; ++ng) {
            int n = ng*16 + (l & 15);
            #pragma unroll
            for (int r = 0; r < 4; ++r)
                Tb[(size_t)(rw + r) * 64 + n] = f2bf(acc[ng][r]);
        }
    } else if (b < 192) {
        // gram = C^T C
        int j   = b - 128;
        int i   = tid & 63;
        int seg = tid >> 6;
        float p = 0.f;
        for (int k = seg * 192; k < seg * 192 + 192; ++k)
            p += C[k * NC + i] * C[k * NC + j];
        float (*red)[64] = (float(*)[64])smem_raw;
        red[seg][i] = p;
        __syncthreads();
        if (seg == 0)
            gram[i * NC + j] = red[0][i] + red[1][i] + red[2][i] + red[3][i];
    } else {
        // U-partial = C^T[kslice] @ W[kslice][128 cols] (f32, verified body)
        int q  = b - 192;
        int nt = q >> 2, ks = q & 3;
        int n0 = nt * 128, kb = ks * 192;
        float (*Cu)[68]  = (float(*)[68])smem_raw;               // [32][68]
        float (*Wu)[132] = (float(*)[132])(smem_raw + 8704);     // [32][132]
        int tx = tid & 15, ty = tid >> 4;
        float4 a0[4], a1[4];
        #pragma unroll
        for (int i = 0; i < 4; ++i) { a0[i] = make_float4(0,0,0,0); a1[i] = make_float4(0,0,0,0); }
        for (int kc = kb; kc < kb + 192; kc += 32) {
            __syncthreads();
            {   int i4 = tid & 15, kk = tid >> 4;
                *((float4*)&Cu[kk][i4*4])    = *((const float4*)(C + (size_t)(kc+kk)*64 + i4*4));
                *((float4*)&Cu[kk+16][i4*4]) = *((const float4*)(C + (size_t)(kc+kk+16)*64 + i4*4));
            }
            {   int nf = tid & 31, kq2 = tid >> 5;
                #pragma unroll
                for (int u = 0; u < 4; ++u) {
                    int k = kq2 + u * 8;
                    int n = n0 + nf * 4;
                    float4 v = {0.f, 0.f, 0.f, 0.f};
                    if (n < NY) v = *((const float4*)(W + (size_t)(kc + k) * NY + n));
                    *((float4*)&Wu[k][nf*4]) = v;
                }
            }
            __syncthreads();
            #pragma unroll 8
            for (int k = 0; k < 32; ++k) {
                float4 ci = *((float4*)&Cu[k][ty*4]);
                float4 w0 = *((float4*)&Wu[k][tx*8]);
                float4 w1 = *((float4*)&Wu[k][tx*8+4]);
                FMA4(a0[0], ci.x, w0); FMA4(a1[0], ci.x, w1);
                FMA4(a0[1], ci.y, w0); FMA4(a1[1], ci.y, w1);
                FMA4(a0[2], ci.z, w0); FMA4(a1[2], ci.z, w1);
                FMA4(a0[3], ci.w, w0); FMA4(a1[3], ci.w, w1);
            }
        }
        float* Ups = Up + (size_t)ks * 64000;
        #pragma unroll
        for (int i = 0; i < 4; ++i) {
            int irow = ty * 4 + i;
            int n = n0 + tx * 8;
            if (n < NY)     *((float4*)(Ups + (size_t)irow * NY + n))     = a0[i];
            if (n + 4 < NY) *((float4*)(Ups + (size_t)irow * NY + n + 4)) = a1[i];
        }
    }
}

// ============ K2: inv (block 0) || score partials (blocks 1..16, f32) ============
__global__ __launch_bounds__(256) void k_phaseB(
    const float* __restrict__ gram, const float* __restrict__ cmP,
    const float* __restrict__ C, float* __restrict__ ginv,
    float* __restrict__ SP) {
    __shared__ __align__(16) char smem_raw[52224];
    int blk = blockIdx.x;
    int tid = threadIdx.x;
    if (blk == 0) {
        // register-resident Gauss-Jordan (verified R3 body)
        int c = tid & 63;
        int q = tid >> 6;
        float a[16], bb[16];
        #pragma unroll
        for (int i = 0; i < 16; ++i) {
            int r = q * 16 + i;
            a[i]  = gram[r * 64 + c];
            bb[i] = (r == c) ? 1.f : 0.f;
        }
        __shared__ float asr[2][64];
        __shared__ float bsr[2][64];
        for (int p = 0; p < 64; ++p) {
            int qp  = p >> 4;
            int lp  = p & 15;
            int par = p & 1;
            if (q == qp) {
                float ap = 0.f, bp = 0.f;
                #pragma unroll
                for (int i = 0; i < 16; ++i)
                    if (i == lp) { ap = a[i]; bp = bb[i]; }
                float App = __shfl(ap, p);
                float s   = 1.0f / App;
                asr[par][c] = ap * s;
                bsr[par][c] = bp * s;
            }
            __syncthreads();
            float as_ = asr[par][c];
            float bs_ = bsr[par][c];
            #pragma unroll
            for (int i = 0; i < 16; ++i) {
                float f = __shfl(a[i], p);
                bool isp = (q == qp) && (i == lp);
                a[i]  = isp ? as_ : fmaf(-f, as_, a[i]);
                bb[i] = isp ? bs_ : fmaf(-f, bs_, bb[i]);
            }
        }
        #pragma unroll
        for (int i = 0; i < 16; ++i)
            ginv[(q * 16 + i) * 64 + c] = bb[i];
    } else {
        // SP-partial = cm[128 rows][192-k slice] @ C; cm = 0.01*sum(4 partials)
        int q = blk - 1;
        int tile = q >> 2, ks = q & 3;
        int r0 = tile * 128, kb = ks * 192;
        float (*Mr)[68] = (float(*)[68])smem_raw;                 // [128][68]
        float (*Cs)[68] = (float(*)[68])(smem_raw + 128*68*4);    // [64][68]
        int tx = tid & 15, ty = tid >> 4;
        float4 acc[8];
        #pragma unroll
        for (int r = 0; r < 8; ++r) acc[r] = make_float4(0.f,0.f,0.f,0.f);
        for (int kc = 0; kc < 192; kc += 64) {
            __syncthreads();
            #pragma unroll
            for (int p = 0; p < 8; ++p) {
                int f = tid + p * 256;
                int row = f >> 4, k4 = f & 15;
                int gr = r0 + row;
                int grc = gr < NCL ? gr : (NCL - 1);
                size_t off = (size_t)grc*DD + kb + kc + k4*4;
                float4 c0 = *((const float4*)(cmP + off));
                float4 c1 = *((const float4*)(cmP + 384000 + off));
                float4 c2 = *((const float4*)(cmP + 768000 + off));
                float4 c3 = *((const float4*)(cmP + 1152000 + off));
                float4 m;
                m.x = (c0.x+c1.x+c2.x+c3.x) * 0.01f;
                m.y = (c0.y+c1.y+c2.y+c3.y) * 0.01f;
                m.z = (c0.z+c1.z+c2.z+c3.z) * 0.01f;
                m.w = (c0.w+c1.w+c2.w+c3.w) * 0.01f;
                *((float4*)&Mr[row][k4*4]) = m;
            }
            #pragma unroll
            for (int p = 0; p < 4; ++p) {
                int f = tid + p * 256;
                int k = f >> 4, c4 = f & 15;
                *((float4*)&Cs[k][c4*4]) =
                    *((const float4*)(C + (size_t)(kb+kc+k)*64 + c4*4));
            }
            __syncthreads();
            for (int k0 = 0; k0 < 64; k0 += 4) {
                float4 cv0 = *((float4*)&Cs[k0+0][tx*4]);
                float4 cv1 = *((float4*)&Cs[k0+1][tx*4]);
                float4 cv2 = *((float4*)&Cs[k0+2][tx*4]);
                float4 cv3 = *((float4*)&Cs[k0+3][tx*4]);
                #pragma unroll
                for (int r = 0; r < 8; ++r) {
                    float4 xv = *((float4*)&Mr[ty*8+r][k0]);
                    FMA4(acc[r], xv.x, cv0);
                    FMA4(acc[r], xv.y, cv1);
                    FMA4(acc[r], xv.z, cv2);
                    FMA4(acc[r], xv.w, cv3);
                }
            }
        }
        float* SPs = SP + (size_t)ks * 32000;
        #pragma unroll
        for (int r = 0; r < 8; ++r) {
            int row = r0 + ty * 8 + r;
            if (row < NCL)
                *((float4*)(SPs + (size_t)row * 64 + tx*4)) = acc[r];
        }
    }
}

// ====== K3: Vb = bf16[(Ginv @ sum Up)^T] granules (0..15) || sparse (16) ======
__global__ __launch_bounds__(256) void k_vc(
    const float* __restrict__ ginv, const float* __restrict__ Up,
    float* __restrict__ SP, unsigned short* __restrict__ Vb,
    float* __restrict__ out2) {
    __shared__ __align__(16) char smem_raw[34816];
    int blk = blockIdx.x, tid = threadIdx.x;
    if (blk == 16) {
        // sparse losses (verified body)
        __shared__ float colred[4][64];
        __shared__ float rn[64];
        __shared__ float trc[64];
        __shared__ float r1[4], r2[4];
        const float* SP0 = SP;
        const float* SP1 = SP + 32000;
        const float* SP2 = SP + 64000;
        const float* SP3 = SP + 96000;
        int c = tid & 63, seg = tid >> 6;
        float p = 0.f;
        for (int r = seg; r < NCL; r += 4) {
            int off = r * 64 + c;
            float s = fabsf(SP0[off] + SP1[off] + SP2[off] + SP3[off]);
            SP[off] = s;
            p += s * s;
        }
        colred[seg][c] = p;
        __syncthreads();
        if (seg == 0) {
            float n2  = colred[0][c] + colred[1][c] + colred[2][c] + colred[3][c];
            float inv = 1.0f / fmaxf(sqrtf(n2), EPSN);
            rn[c]  = inv;
            trc[c] = n2 * inv * inv;
        }
        __syncthreads();
        float l1p = 0.f, l2p = 0.f;
        for (int r = tid; r < NCL; r += 256) {
            float rs = 0.f;
            #pragma unroll
            for (int cc = 0; cc < 64; ++cc)
                rs += SP[r * 64 + cc] * rn[cc];
            l1p += rs;
            l2p += rs * rs;
        }
        #pragma unroll
        for (int off = 32; off > 0; off >>= 1) {
            l1p += __shfl_down(l1p, off);
            l2p += __shfl_down(l2p, off);
        }
        int wave = tid >> 6, lane = tid & 63;
        if (lane == 0) { r1[wave] = l1p; r2[wave] = l2p; }
        __syncthreads();
        if (tid == 0) {
            float L1 = r1[0] + r1[1] + r1[2] + r1[3];
            float L2 = r2[0] + r2[1] + r2[2] + r2[3];
            float tr = 0.f;
            #pragma unroll
            for (int cc = 0; cc < 64; ++cc) tr += trc[cc];
            out2[0] = L1;
            out2[1] = L2 - tr;
        }
        return;
    }
    // V = Ginv @ Usum (f32 compute), emitted TRANSPOSED bf16: Vb[n*64 + k],
    // i.e. the B-fragment layout ypred's MFMA wants. n >= 1000 -> zeros.
    float (*Us)[68] = (float(*)[68])smem_raw;                     // [64][68]
    float (*Gs)[68] = (float(*)[68])(smem_raw + 64*68*4);         // [64][68]
    int c0 = blk * 64;
    int tx = tid & 15, ty = tid >> 4;
    const float* Up0 = Up;
    const float* Up1 = Up + 64000;
    const float* Up2 = Up + 128000;
    const float* Up3 = Up + 192000;
    #pragma unroll
    for (int p = 0; p < 4; ++p) {
        int f = tid + p * 256;
        int j = f >> 4, n4 = f & 15;
        int n = c0 + n4 * 4;
        float4 v = {0.f, 0.f, 0.f, 0.f};
        if (n < NY) {
            float4 u0 = *((const float4*)(Up0 + (size_t)j * NY + n));
            float4 u1 = *((const float4*)(Up1 + (size_t)j * NY + n));
            float4 u2 = *((const float4*)(Up2 + (size_t)j * NY + n));
            float4 u3 = *((const float4*)(Up3 + (size_t)j * NY + n));
            v.x = u0.x + u1.x + u2.x + u3.x;
            v.y = u0.y + u1.y + u2.y + u3.y;
            v.z = u0.z + u1.z + u2.z + u3.z;
            v.w = u0.w + u1.w + u2.w + u3.w;
        }
        *((float4*)&Us[j][n4*4]) = v;
        *((float4*)&Gs[j][n4*4]) = *((const float4*)(ginv + (size_t)j * 64 + n4*4));
    }
    __syncthreads();
    float4 acc[4];
    #pragma unroll
    for (int i = 0; i < 4; ++i) acc[i] = make_float4(0.f,0.f,0.f,0.f);
    for (int j0 = 0; j0 < 64; j0 += 4) {
        #pragma unroll
        for (int jj = 0; jj < 4; ++jj) {
            float4 g = *((float4*)&Gs[j0+jj][ty*4]);   // Ginv symmetric
            float4 u = *((float4*)&Us[j0+jj][tx*4]);
            FMA4(acc[0], g.x, u);
            FMA4(acc[1], g.y, u);
            FMA4(acc[2], g.z, u);
            FMA4(acc[3], g.w, u);
        }
    }
    // acc[i].q = V[i=ty*4+i][n=c0+tx*4+q] -> Vb[n][i]
    #pragma unroll
    for (int i = 0; i < 4; ++i) {
        int krow = ty * 4 + i;
        Vb[(size_t)(c0 + tx*4 + 0) * 64 + krow] = f2bf(acc[i].x);
        Vb[(size_t)(c0 + tx*4 + 1) * 64 + krow] = f2bf(acc[i].y);
        Vb[(size_t)(c0 + tx*4 + 2) * 64 + krow] = f2bf(acc[i].z);
        Vb[(size_t)(c0 + tx*4 + 3) * 64 + krow] = f2bf(acc[i].w);
    }
}

// ============ K4: y = T @ V + b via MFMA, 128x128 tile, zero LDS ============
__global__ __launch_bounds__(256) void k_ypred(
    const uint4* __restrict__ Tb, const uint4* __restrict__ Vbq,
    const float* __restrict__ bh, float* __restrict__ Y) {
    int blk = blockIdx.x, tid = threadIdx.x;
    int rb = blk >> 3, cb = blk & 7;
    int r0g = rb * 128, c0g = cb * 128;
    int w = tid >> 6, l = tid & 63;
    int wr = (w >> 1) * 64, wc = (w & 1) * 64;
    int kq = l >> 4, ln = l & 15;
    f32x4 acc[4][4];
    #pragma unroll
    for (int rg = 0; rg < 4; ++rg)
        #pragma unroll
        for (int ng = 0; ng < 4; ++ng) acc[rg][ng] = (f32x4){0.f,0.f,0.f,0.f};
    #pragma unroll
    for (int ks = 0; ks < 2; ++ks) {
        B8 a[4], bb[4];
        #pragma unroll
        for (int rg = 0; rg < 4; ++rg) {
            int row = r0g + wr + rg*16 + ln;
            a[rg].q = Tb[(size_t)row * 8 + ks*4 + kq];     // T[row][k..k+7] bf16
        }
        #pragma unroll
        for (int ng = 0; ng < 4; ++ng) {
            int n = c0g + wc + ng*16 + ln;
            bb[ng].q = Vbq[(size_t)n * 8 + ks*4 + kq];     // V^T[n][k..k+7] bf16
        }
        #pragma unroll
        for (int rg = 0; rg < 4; ++rg)
            #pragma unroll
            for (int ng = 0; ng < 4; ++ng)
                acc[rg][ng] = __builtin_amdgcn_mfma_f32_16x16x32_bf16(
                    a[rg].v, bb[ng].v, acc[rg][ng], 0, 0, 0);
    }
    #pragma unroll
    for (int ng = 0; ng < 4; ++ng) {
        int n = c0g + wc + ng*16 + ln;
        if (n < NY) {
            float bias = bh[n];
            #pragma unroll
            for (int rg = 0; rg < 4; ++rg) {
                int row = r0g + wr + rg*16 + kq*4;
                #pragma unroll
                for (int r = 0; r < 4; ++r)
                    Y[(size_t)(row + r) * NY + n] = acc[rg][ng][r] + bias;
            }
        }
    }
}

extern "C" void kernel_launch(void* const* d_in, const int* in_sizes, int n_in,
                              void* d_out, int out_size, void* d_ws, size_t ws_size,
                              hipStream_t stream) {
    const float* X        = (const float*)d_in[0];   // [8192,768]
    const float* clusters = (const float*)d_in[1];   // [500,100,768]
    const float* C        = (const float*)d_in[2];   // [768,64]
    const float* W        = (const float*)d_in[3];   // [768,1000]
    const float* bh       = (const float*)d_in[4];   // [1000]
    float* out = (float*)d_out;                      // y_pred, L1, L2
    float* ws  = (float*)d_ws;

    float* cmP  = ws;                    // 4 x 384000 = 1,536,000
    float* gram = cmP  + 1536000;        // 4096
    float* ginv = gram + 4096;           // 4096
    float* Up   = ginv + 4096;           // 4 x 64000 = 256000
    float* SP   = Up   + 256000;         // 4 x 32000 = 128000
    float* CbF  = SP   + 128000;         // 24576 floats  (96 KB bf16 granules)
    float* TbF  = CbF  + 24576;          // 262144 floats (1 MB bf16)
    float* VbF  = TbF  + 262144;         // 32768 floats  (128 KB bf16)

    uint4*          Cb  = (uint4*)CbF;
    unsigned short* Tb  = (unsigned short*)TbF;
    unsigned short* Vb  = (unsigned short*)VbF;

    k_pre   <<<dim3(1524), dim3(256), 0, stream>>>(clusters, C, cmP, Cb);
    k_gemms <<<dim3(224),  dim3(256), 0, stream>>>(C, W, X, Cb, gram, Up, Tb);
    k_phaseB<<<dim3(17),   dim3(256), 0, stream>>>(gram, cmP, C, ginv, SP);
    k_vc    <<<dim3(17),   dim3(256), 0, stream>>>(ginv, Up, SP, Vb, out + (size_t)BS * NY);
    k_ypred <<<dim3(512),  dim3(256), 0, stream>>>((const uint4*)Tb, (const uint4*)Vb, bh, out);
}

// Round 11
// 161.569 us; speedup vs baseline: 1.1459x; 1.0139x over previous
//
#include <hip/hip_runtime.h>
#include <hip/hip_bf16.h>
#include <math.h>

#define BS   8192
#define DD   768
#define NC   64
#define NCL  500
#define CS   100
#define NY   1000
#define EPSN 1e-12f

typedef __attribute__((ext_vector_type(8))) short bf16x8;
typedef __attribute__((ext_vector_type(4))) float f32x4;

union B8 { unsigned u[4]; bf16x8 v; uint4 q; };

__device__ inline unsigned short f2bf(float x) {
    __hip_bfloat16 h = __float2bfloat16(x);
    return *reinterpret_cast<unsigned short*>(&h);
}
__device__ inline unsigned pk2(float a, float b) {
    return (unsigned)f2bf(a) | ((unsigned)f2bf(b) << 16);
}

#define FMA4(acc, s, v) { (acc).x = fmaf((s), (v).x, (acc).x); \
                          (acc).y = fmaf((s), (v).y, (acc).y); \
                          (acc).z = fmaf((s), (v).z, (acc).z); \
                          (acc).w = fmaf((s), (v).w, (acc).w); }

// ============ K0: cmean s-split partials (1500) || Cb bf16 pack (24) ============
__global__ __launch_bounds__(256) void k_pre(
    const float* __restrict__ clusters, const float* __restrict__ C,
    float* __restrict__ cmP, uint4* __restrict__ Cb) {
    int b = blockIdx.x, tid = threadIdx.x;
    if (b < 1500) {
        // partial sum over 25 of the 100 cluster samples; 5 loads in flight
        int sp  = b & 3;
        int idx = (b >> 2) * 256 + tid;          // 375*256 == 500*192
        int r  = idx / 192;
        int d4 = idx % 192;
        const float4* base = (const float4*)clusters
                           + (size_t)r * CS * 192 + (size_t)sp * 25 * 192 + d4;
        float4 a0={0,0,0,0},a1={0,0,0,0},a2={0,0,0,0},a3={0,0,0,0},a4={0,0,0,0};
        for (int s = 0; s < 25; s += 5) {
            float4 v0 = base[(size_t)(s+0)*192];
            float4 v1 = base[(size_t)(s+1)*192];
            float4 v2 = base[(size_t)(s+2)*192];
            float4 v3 = base[(size_t)(s+3)*192];
            float4 v4 = base[(size_t)(s+4)*192];
            a0.x+=v0.x; a0.y+=v0.y; a0.z+=v0.z; a0.w+=v0.w;
            a1.x+=v1.x; a1.y+=v1.y; a1.z+=v1.z; a1.w+=v1.w;
            a2.x+=v2.x; a2.y+=v2.y; a2.z+=v2.z; a2.w+=v2.w;
            a3.x+=v3.x; a3.y+=v3.y; a3.z+=v3.z; a3.w+=v3.w;
            a4.x+=v4.x; a4.y+=v4.y; a4.z+=v4.z; a4.w+=v4.w;
        }
        float4 o;
        o.x = a0.x+a1.x+a2.x+a3.x+a4.x;
        o.y = a0.y+a1.y+a2.y+a3.y+a4.y;
        o.z = a0.z+a1.z+a2.z+a3.z+a4.z;
        o.w = a0.w+a1.w+a2.w+a3.w+a4.w;
        ((float4*)(cmP + (size_t)sp * 384000))[idx] = o;   // RAW sum; *0.01 at use
    } else {
        // Cb: bf16 B-fragment granules for mfma_16x16x32
        int ks = b - 1500;                        // 0..23
        int kg = tid >> 6, n = tid & 63;
        const float* cp = C + (size_t)(ks*32 + kg*8) * 64 + n;
        uint4 g;
        g.x = pk2(cp[0],     cp[64]);
        g.y = pk2(cp[2*64],  cp[3*64]);
        g.z = pk2(cp[4*64],  cp[5*64]);
        g.w = pk2(cp[6*64],  cp[7*64]);
        Cb[(ks*4 + kg)*64 + n] = g;
    }
}

// ====== K1: tmat MFMA (128) || gram k-split partials (256) || U f32 ksplit (32) ======
__global__ __launch_bounds__(256) void k_gemms(
    const float* __restrict__ C, const float* __restrict__ W,
    const float* __restrict__ X, const uint4* __restrict__ Cb,
    float* __restrict__ gramP, float* __restrict__ Up,
    unsigned short* __restrict__ Tb) {
    __shared__ __align__(16) char smem_raw[25600];
    int b = blockIdx.x, tid = threadIdx.x;

    if (b < 128) {
        // T = X @ C via MFMA, zero LDS (verified R9 body)
        int r0 = b * 64;
        int w  = tid >> 6, l = tid & 63;
        int rowA = r0 + w*16 + (l & 15);
        int kq   = l >> 4;
        const float* xb = X + (size_t)rowA * DD + kq * 8;
        f32x4 acc[4];
        #pragma unroll
        for (int ng = 0; ng < 4; ++ng) acc[ng] = (f32x4){0.f, 0.f, 0.f, 0.f};
        #pragma unroll 2
        for (int ks = 0; ks < 24; ++ks) {
            float4 xa = *((const float4*)(xb + ks*32));
            float4 xc = *((const float4*)(xb + ks*32 + 4));
            B8 a;
            a.u[0] = pk2(xa.x, xa.y); a.u[1] = pk2(xa.z, xa.w);
            a.u[2] = pk2(xc.x, xc.y); a.u[3] = pk2(xc.z, xc.w);
            const uint4* cbase = Cb + (ks*4 + kq)*64 + (l & 15);
            B8 b0, b1, b2, b3;
            b0.q = cbase[0];  b1.q = cbase[16];
            b2.q = cbase[32]; b3.q = cbase[48];
            acc[0] = __builtin_amdgcn_mfma_f32_16x16x32_bf16(a.v, b0.v, acc[0], 0, 0, 0);
            acc[1] = __builtin_amdgcn_mfma_f32_16x16x32_bf16(a.v, b1.v, acc[1], 0, 0, 0);
            acc[2] = __builtin_amdgcn_mfma_f32_16x16x32_bf16(a.v, b2.v, acc[2], 0, 0, 0);
            acc[3] = __builtin_amdgcn_mfma_f32_16x16x32_bf16(a.v, b3.v, acc[3], 0, 0, 0);
        }
        int rw = r0 + w*16 + (l >> 4) * 4;
        #pragma unroll
        for (int ng = 0; ng < 4; ++ng) {
            int n = ng*16 + (l & 15);
            #pragma unroll
            for (int r = 0; r < 4; ++r)
                Tb[(size_t)(rw + r) * 64 + n] = f2bf(acc[ng][r]);
        }
    } else if (b < 384) {
        // gram k-split: block (j, ks) computes partial gram col j over 192 k.
        // R10 change: was 64 blocks x 192-iter serial load chain (latency bomb);
        // now 256 blocks x 48 iters. inv sums the 4 partials at load.
        int q  = b - 128;
        int j  = q & 63, ks = q >> 6;
        int i   = tid & 63;
        int seg = tid >> 6;
        int k0  = ks * 192 + seg * 48;
        float p = 0.f;
        for (int k = k0; k < k0 + 48; ++k)
            p += C[k * NC + i] * C[k * NC + j];
        float (*red)[64] = (float(*)[64])smem_raw;
        red[seg][i] = p;
        __syncthreads();
        if (seg == 0)
            gramP[(size_t)ks * 4096 + i * NC + j] =
                red[0][i] + red[1][i] + red[2][i] + red[3][i];
    } else {
        // U-partial = C^T[kslice] @ W[kslice][128 cols] (f32, verified body)
        int q  = b - 384;
        int nt = q >> 2, ks = q & 3;
        int n0 = nt * 128, kb = ks * 192;
        float (*Cu)[68]  = (float(*)[68])smem_raw;               // [32][68]
        float (*Wu)[132] = (float(*)[132])(smem_raw + 8704);     // [32][132]
        int tx = tid & 15, ty = tid >> 4;
        float4 a0[4], a1[4];
        #pragma unroll
        for (int i = 0; i < 4; ++i) { a0[i] = make_float4(0,0,0,0); a1[i] = make_float4(0,0,0,0); }
        for (int kc = kb; kc < kb + 192; kc += 32) {
            __syncthreads();
            {   int i4 = tid & 15, kk = tid >> 4;
                *((float4*)&Cu[kk][i4*4])    = *((const float4*)(C + (size_t)(kc+kk)*64 + i4*4));
                *((float4*)&Cu[kk+16][i4*4]) = *((const float4*)(C + (size_t)(kc+kk+16)*64 + i4*4));
            }
            {   int nf = tid & 31, kq2 = tid >> 5;
                #pragma unroll
                for (int u = 0; u < 4; ++u) {
                    int k = kq2 + u * 8;
                    int n = n0 + nf * 4;
                    float4 v = {0.f, 0.f, 0.f, 0.f};
                    if (n < NY) v = *((const float4*)(W + (size_t)(kc + k) * NY + n));
                    *((float4*)&Wu[k][nf*4]) = v;
                }
            }
            __syncthreads();
            #pragma unroll 8
            for (int k = 0; k < 32; ++k) {
                float4 ci = *((float4*)&Cu[k][ty*4]);
                float4 w0 = *((float4*)&Wu[k][tx*8]);
                float4 w1 = *((float4*)&Wu[k][tx*8+4]);
                FMA4(a0[0], ci.x, w0); FMA4(a1[0], ci.x, w1);
                FMA4(a0[1], ci.y, w0); FMA4(a1[1], ci.y, w1);
                FMA4(a0[2], ci.z, w0); FMA4(a1[2], ci.z, w1);
                FMA4(a0[3], ci.w, w0); FMA4(a1[3], ci.w, w1);
            }
        }
        float* Ups = Up + (size_t)ks * 64000;
        #pragma unroll
        for (int i = 0; i < 4; ++i) {
            int irow = ty * 4 + i;
            int n = n0 + tx * 8;
            if (n < NY)     *((float4*)(Ups + (size_t)irow * NY + n))     = a0[i];
            if (n + 4 < NY) *((float4*)(Ups + (size_t)irow * NY + n + 4)) = a1[i];
        }
    }
}

// ============ K2: inv (block 0) || score partials (blocks 1..16, f32) ============
__global__ __launch_bounds__(256) void k_phaseB(
    const float* __restrict__ gramP, const float* __restrict__ cmP,
    const float* __restrict__ C, float* __restrict__ ginv,
    float* __restrict__ SP) {
    __shared__ __align__(16) char smem_raw[52224];
    int blk = blockIdx.x;
    int tid = threadIdx.x;
    if (blk == 0) {
        // register-resident Gauss-Jordan; gram = sum of 4 k-split partials
        int c = tid & 63;
        int q = tid >> 6;
        float a[16], bb[16];
        #pragma unroll
        for (int i = 0; i < 16; ++i) {
            int r = q * 16 + i;
            size_t off = (size_t)r * 64 + c;
            a[i]  = gramP[off] + gramP[4096 + off] + gramP[8192 + off] + gramP[12288 + off];
            bb[i] = (r == c) ? 1.f : 0.f;
        }
        __shared__ float asr[2][64];
        __shared__ float bsr[2][64];
        for (int p = 0; p < 64; ++p) {
            int qp  = p >> 4;
            int lp  = p & 15;
            int par = p & 1;
            if (q == qp) {
                float ap = 0.f, bp = 0.f;
                #pragma unroll
                for (int i = 0; i < 16; ++i)
                    if (i == lp) { ap = a[i]; bp = bb[i]; }
                float App = __shfl(ap, p);
                float s   = 1.0f / App;
                asr[par][c] = ap * s;
                bsr[par][c] = bp * s;
            }
            __syncthreads();
            float as_ = asr[par][c];
            float bs_ = bsr[par][c];
            #pragma unroll
            for (int i = 0; i < 16; ++i) {
                float f = __shfl(a[i], p);
                bool isp = (q == qp) && (i == lp);
                a[i]  = isp ? as_ : fmaf(-f, as_, a[i]);
                bb[i] = isp ? bs_ : fmaf(-f, bs_, bb[i]);
            }
        }
        #pragma unroll
        for (int i = 0; i < 16; ++i)
            ginv[(q * 16 + i) * 64 + c] = bb[i];
    } else {
        // SP-partial = cm[128 rows][192-k slice] @ C; cm = 0.01*sum(4 partials)
        int q = blk - 1;
        int tile = q >> 2, ks = q & 3;
        int r0 = tile * 128, kb = ks * 192;
        float (*Mr)[68] = (float(*)[68])smem_raw;                 // [128][68]
        float (*Cs)[68] = (float(*)[68])(smem_raw + 128*68*4);    // [64][68]
        int tx = tid & 15, ty = tid >> 4;
        float4 acc[8];
        #pragma unroll
        for (int r = 0; r < 8; ++r) acc[r] = make_float4(0.f,0.f,0.f,0.f);
        for (int kc = 0; kc < 192; kc += 64) {
            __syncthreads();
            #pragma unroll
            for (int p = 0; p < 8; ++p) {
                int f = tid + p * 256;
                int row = f >> 4, k4 = f & 15;
                int gr = r0 + row;
                int grc = gr < NCL ? gr : (NCL - 1);
                size_t off = (size_t)grc*DD + kb + kc + k4*4;
                float4 c0 = *((const float4*)(cmP + off));
                float4 c1 = *((const float4*)(cmP + 384000 + off));
                float4 c2 = *((const float4*)(cmP + 768000 + off));
                float4 c3 = *((const float4*)(cmP + 1152000 + off));
                float4 m;
                m.x = (c0.x+c1.x+c2.x+c3.x) * 0.01f;
                m.y = (c0.y+c1.y+c2.y+c3.y) * 0.01f;
                m.z = (c0.z+c1.z+c2.z+c3.z) * 0.01f;
                m.w = (c0.w+c1.w+c2.w+c3.w) * 0.01f;
                *((float4*)&Mr[row][k4*4]) = m;
            }
            #pragma unroll
            for (int p = 0; p < 4; ++p) {
                int f = tid + p * 256;
                int k = f >> 4, c4 = f & 15;
                *((float4*)&Cs[k][c4*4]) =
                    *((const float4*)(C + (size_t)(kb+kc+k)*64 + c4*4));
            }
            __syncthreads();
            for (int k0 = 0; k0 < 64; k0 += 4) {
                float4 cv0 = *((float4*)&Cs[k0+0][tx*4]);
                float4 cv1 = *((float4*)&Cs[k0+1][tx*4]);
                float4 cv2 = *((float4*)&Cs[k0+2][tx*4]);
                float4 cv3 = *((float4*)&Cs[k0+3][tx*4]);
                #pragma unroll
                for (int r = 0; r < 8; ++r) {
                    float4 xv = *((float4*)&Mr[ty*8+r][k0]);
                    FMA4(acc[r], xv.x, cv0);
                    FMA4(acc[r], xv.y, cv1);
                    FMA4(acc[r], xv.z, cv2);
                    FMA4(acc[r], xv.w, cv3);
                }
            }
        }
        float* SPs = SP + (size_t)ks * 32000;
        #pragma unroll
        for (int r = 0; r < 8; ++r) {
            int row = r0 + ty * 8 + r;
            if (row < NCL)
                *((float4*)(SPs + (size_t)row * 64 + tx*4)) = acc[r];
        }
    }
}

// ====== K3: Vb = bf16[(Ginv @ sum Up)^T] granules (0..15) || sparse (16) ======
__global__ __launch_bounds__(256) void k_vc(
    const float* __restrict__ ginv, const float* __restrict__ Up,
    float* __restrict__ SP, unsigned short* __restrict__ Vb,
    float* __restrict__ out2) {
    __shared__ __align__(16) char smem_raw[34816];
    int blk = blockIdx.x, tid = threadIdx.x;
    if (blk == 16) {
        // sparse losses (verified body)
        __shared__ float colred[4][64];
        __shared__ float rn[64];
        __shared__ float trc[64];
        __shared__ float r1[4], r2[4];
        const float* SP0 = SP;
        const float* SP1 = SP + 32000;
        const float* SP2 = SP + 64000;
        const float* SP3 = SP + 96000;
        int c = tid & 63, seg = tid >> 6;
        float p = 0.f;
        for (int r = seg; r < NCL; r += 4) {
            int off = r * 64 + c;
            float s = fabsf(SP0[off] + SP1[off] + SP2[off] + SP3[off]);
            SP[off] = s;
            p += s * s;
        }
        colred[seg][c] = p;
        __syncthreads();
        if (seg == 0) {
            float n2  = colred[0][c] + colred[1][c] + colred[2][c] + colred[3][c];
            float inv = 1.0f / fmaxf(sqrtf(n2), EPSN);
            rn[c]  = inv;
            trc[c] = n2 * inv * inv;
        }
        __syncthreads();
        float l1p = 0.f, l2p = 0.f;
        for (int r = tid; r < NCL; r += 256) {
            float rs = 0.f;
            #pragma unroll
            for (int cc = 0; cc < 64; ++cc)
                rs += SP[r * 64 + cc] * rn[cc];
            l1p += rs;
            l2p += rs * rs;
        }
        #pragma unroll
        for (int off = 32; off > 0; off >>= 1) {
            l1p += __shfl_down(l1p, off);
            l2p += __shfl_down(l2p, off);
        }
        int wave = tid >> 6, lane = tid & 63;
        if (lane == 0) { r1[wave] = l1p; r2[wave] = l2p; }
        __syncthreads();
        if (tid == 0) {
            float L1 = r1[0] + r1[1] + r1[2] + r1[3];
            float L2 = r2[0] + r2[1] + r2[2] + r2[3];
            float tr = 0.f;
            #pragma unroll
            for (int cc = 0; cc < 64; ++cc) tr += trc[cc];
            out2[0] = L1;
            out2[1] = L2 - tr;
        }
        return;
    }
    // V = Ginv @ Usum (f32), emitted transposed bf16 (B-fragment layout)
    float (*Us)[68] = (float(*)[68])smem_raw;                     // [64][68]
    float (*Gs)[68] = (float(*)[68])(smem_raw + 64*68*4);         // [64][68]
    int c0 = blk * 64;
    int tx = tid & 15, ty = tid >> 4;
    const float* Up0 = Up;
    const float* Up1 = Up + 64000;
    const float* Up2 = Up + 128000;
    const float* Up3 = Up + 192000;
    #pragma unroll
    for (int p = 0; p < 4; ++p) {
        int f = tid + p * 256;
        int j = f >> 4, n4 = f & 15;
        int n = c0 + n4 * 4;
        float4 v = {0.f, 0.f, 0.f, 0.f};
        if (n < NY) {
            float4 u0 = *((const float4*)(Up0 + (size_t)j * NY + n));
            float4 u1 = *((const float4*)(Up1 + (size_t)j * NY + n));
            float4 u2 = *((const float4*)(Up2 + (size_t)j * NY + n));
            float4 u3 = *((const float4*)(Up3 + (size_t)j * NY + n));
            v.x = u0.x + u1.x + u2.x + u3.x;
            v.y = u0.y + u1.y + u2.y + u3.y;
            v.z = u0.z + u1.z + u2.z + u3.z;
            v.w = u0.w + u1.w + u2.w + u3.w;
        }
        *((float4*)&Us[j][n4*4]) = v;
        *((float4*)&Gs[j][n4*4]) = *((const float4*)(ginv + (size_t)j * 64 + n4*4));
    }
    __syncthreads();
    float4 acc[4];
    #pragma unroll
    for (int i = 0; i < 4; ++i) acc[i] = make_float4(0.f,0.f,0.f,0.f);
    for (int j0 = 0; j0 < 64; j0 += 4) {
        #pragma unroll
        for (int jj = 0; jj < 4; ++jj) {
            float4 g = *((float4*)&Gs[j0+jj][ty*4]);   // Ginv symmetric
            float4 u = *((float4*)&Us[j0+jj][tx*4]);
            FMA4(acc[0], g.x, u);
            FMA4(acc[1], g.y, u);
            FMA4(acc[2], g.z, u);
            FMA4(acc[3], g.w, u);
        }
    }
    #pragma unroll
    for (int i = 0; i < 4; ++i) {
        int krow = ty * 4 + i;
        Vb[(size_t)(c0 + tx*4 + 0) * 64 + krow] = f2bf(acc[i].x);
        Vb[(size_t)(c0 + tx*4 + 1) * 64 + krow] = f2bf(acc[i].y);
        Vb[(size_t)(c0 + tx*4 + 2) * 64 + krow] = f2bf(acc[i].z);
        Vb[(size_t)(c0 + tx*4 + 3) * 64 + krow] = f2bf(acc[i].w);
    }
}

// ============ K4: y = T @ V + b via MFMA, 128x128 tile, zero LDS ============
__global__ __launch_bounds__(256) void k_ypred(
    const uint4* __restrict__ Tb, const uint4* __restrict__ Vbq,
    const float* __restrict__ bh, float* __restrict__ Y) {
    int blk = blockIdx.x, tid = threadIdx.x;
    int rb = blk >> 3, cb = blk & 7;
    int r0g = rb * 128, c0g = cb * 128;
    int w = tid >> 6, l = tid & 63;
    int wr = (w >> 1) * 64, wc = (w & 1) * 64;
    int kq = l >> 4, ln = l & 15;
    f32x4 acc[4][4];
    #pragma unroll
    for (int rg = 0; rg < 4; ++rg)
        #pragma unroll
        for (int ng = 0; ng < 4; ++ng) acc[rg][ng] = (f32x4){0.f,0.f,0.f,0.f};
    #pragma unroll
    for (int ks = 0; ks < 2; ++ks) {
        B8 a[4], bb[4];
        #pragma unroll
        for (int rg = 0; rg < 4; ++rg) {
            int row = r0g + wr + rg*16 + ln;
            a[rg].q = Tb[(size_t)row * 8 + ks*4 + kq];     // T[row][k..k+7] bf16
        }
        #pragma unroll
        for (int ng = 0; ng < 4; ++ng) {
            int n = c0g + wc + ng*16 + ln;
            bb[ng].q = Vbq[(size_t)n * 8 + ks*4 + kq];     // V^T[n][k..k+7] bf16
        }
        #pragma unroll
        for (int rg = 0; rg < 4; ++rg)
            #pragma unroll
            for (int ng = 0; ng < 4; ++ng)
                acc[rg][ng] = __builtin_amdgcn_mfma_f32_16x16x32_bf16(
                    a[rg].v, bb[ng].v, acc[rg][ng], 0, 0, 0);
    }
    #pragma unroll
    for (int ng = 0; ng < 4; ++ng) {
        int n = c0g + wc + ng*16 + ln;
        if (n < NY) {
            float bias = bh[n];
            #pragma unroll
            for (int rg = 0; rg < 4; ++rg) {
                int row = r0g + wr + rg*16 + kq*4;
                #pragma unroll
                for (int r = 0; r < 4; ++r)
                    Y[(size_t)(row + r) * NY + n] = acc[rg][ng][r] + bias;
            }
        }
    }
}

extern "C" void kernel_launch(void* const* d_in, const int* in_sizes, int n_in,
                              void* d_out, int out_size, void* d_ws, size_t ws_size,
                              hipStream_t stream) {
    const float* X        = (const float*)d_in[0];   // [8192,768]
    const float* clusters = (const float*)d_in[1];   // [500,100,768]
    const float* C        = (const float*)d_in[2];   // [768,64]
    const float* W        = (const float*)d_in[3];   // [768,1000]
    const float* bh       = (const float*)d_in[4];   // [1000]
    float* out = (float*)d_out;                      // y_pred, L1, L2
    float* ws  = (float*)d_ws;

    float* cmP   = ws;                    // 4 x 384000 = 1,536,000
    float* gramP = cmP   + 1536000;       // 4 x 4096 = 16384
    float* ginv  = gramP + 16384;         // 4096
    float* Up    = ginv  + 4096;          // 4 x 64000 = 256000
    float* SP    = Up    + 256000;        // 4 x 32000 = 128000
    float* CbF   = SP    + 128000;        // 24576 floats (Cb granules)
    float* TbF   = CbF   + 24576;         // 262144 floats (Tb bf16)
    float* VbF   = TbF   + 262144;        // 32768 floats (Vb bf16)

    uint4*          Cb  = (uint4*)CbF;
    unsigned short* Tb  = (unsigned short*)TbF;
    unsigned short* Vb  = (unsigned short*)VbF;

    k_pre   <<<dim3(1524), dim3(256), 0, stream>>>(clusters, C, cmP, Cb);
    k_gemms <<<dim3(416),  dim3(256), 0, stream>>>(C, W, X, Cb, gramP, Up, Tb);
    k_phaseB<<<dim3(17),   dim3(256), 0, stream>>>(gramP, cmP, C, ginv, SP);
    k_vc    <<<dim3(17),   dim3(256), 0, stream>>>(ginv, Up, SP, Vb, out + (size_t)BS * NY);
    k_ypred <<<dim3(512),  dim3(256), 0, stream>>>((const uint4*)Tb, (const uint4*)Vb, bh, out);
}

// Round 12
// 158.068 us; speedup vs baseline: 1.1713x; 1.0221x over previous
//
#include <hip/hip_runtime.h>
#include <hip/hip_bf16.h>
#include <math.h>

#define BS   8192
#define DD   768
#define NC   64
#define NCL  500
#define CS   100
#define NY   1000
#define EPSN 1e-12f

typedef __attribute__((ext_vector_type(8))) short bf16x8;
typedef __attribute__((ext_vector_type(4))) float f32x4;

union B8 { unsigned u[4]; bf16x8 v; uint4 q; };

__device__ inline unsigned short f2bf(float x) {
    __hip_bfloat16 h = __float2bfloat16(x);
    return *reinterpret_cast<unsigned short*>(&h);
}
__device__ inline unsigned pk2(float a, float b) {
    return (unsigned)f2bf(a) | ((unsigned)f2bf(b) << 16);
}

#define FMA4(acc, s, v) { (acc).x = fmaf((s), (v).x, (acc).x); \
                          (acc).y = fmaf((s), (v).y, (acc).y); \
                          (acc).z = fmaf((s), (v).z, (acc).z); \
                          (acc).w = fmaf((s), (v).w, (acc).w); }

// ===== K1: cmean partials (1500) || Cb pack (24) || gram ksplit (256) || U (32) =====
// All four roles are mutually independent -> one kernel, BW stream overlaps
// the VALU/LDS roles on separate pipes (m114).
__global__ __launch_bounds__(256) void k_front(
    const float* __restrict__ clusters, const float* __restrict__ C,
    const float* __restrict__ W, float* __restrict__ cmP,
    uint4* __restrict__ Cb, float* __restrict__ gramP,
    float* __restrict__ Up) {
    __shared__ __align__(16) char smem_raw[25600];
    int b = blockIdx.x, tid = threadIdx.x;
    if (b < 1500) {
        // cmean partial over 25 samples; 5 loads in flight (verified R9 body)
        int sp  = b & 3;
        int idx = (b >> 2) * 256 + tid;          // 375*256 == 500*192
        int r  = idx / 192;
        int d4 = idx % 192;
        const float4* base = (const float4*)clusters
                           + (size_t)r * CS * 192 + (size_t)sp * 25 * 192 + d4;
        float4 a0={0,0,0,0},a1={0,0,0,0},a2={0,0,0,0},a3={0,0,0,0},a4={0,0,0,0};
        for (int s = 0; s < 25; s += 5) {
            float4 v0 = base[(size_t)(s+0)*192];
            float4 v1 = base[(size_t)(s+1)*192];
            float4 v2 = base[(size_t)(s+2)*192];
            float4 v3 = base[(size_t)(s+3)*192];
            float4 v4 = base[(size_t)(s+4)*192];
            a0.x+=v0.x; a0.y+=v0.y; a0.z+=v0.z; a0.w+=v0.w;
            a1.x+=v1.x; a1.y+=v1.y; a1.z+=v1.z; a1.w+=v1.w;
            a2.x+=v2.x; a2.y+=v2.y; a2.z+=v2.z; a2.w+=v2.w;
            a3.x+=v3.x; a3.y+=v3.y; a3.z+=v3.z; a3.w+=v3.w;
            a4.x+=v4.x; a4.y+=v4.y; a4.z+=v4.z; a4.w+=v4.w;
        }
        float4 o;
        o.x = a0.x+a1.x+a2.x+a3.x+a4.x;
        o.y = a0.y+a1.y+a2.y+a3.y+a4.y;
        o.z = a0.z+a1.z+a2.z+a3.z+a4.z;
        o.w = a0.w+a1.w+a2.w+a3.w+a4.w;
        ((float4*)(cmP + (size_t)sp * 384000))[idx] = o;   // RAW; *0.01 at use
    } else if (b < 1524) {
        // Cb: bf16 B-fragment granules (verified R9 body)
        int ks = b - 1500;                        // 0..23
        int kg = tid >> 6, n = tid & 63;
        const float* cp = C + (size_t)(ks*32 + kg*8) * 64 + n;
        uint4 g;
        g.x = pk2(cp[0],     cp[64]);
        g.y = pk2(cp[2*64],  cp[3*64]);
        g.z = pk2(cp[4*64],  cp[5*64]);
        g.w = pk2(cp[6*64],  cp[7*64]);
        Cb[(ks*4 + kg)*64 + n] = g;
    } else if (b < 1780) {
        // gram k-split partials (verified R11 body)
        int q  = b - 1524;
        int j  = q & 63, ks = q >> 6;
        int i   = tid & 63;
        int seg = tid >> 6;
        int k0  = ks * 192 + seg * 48;
        float p = 0.f;
        for (int k = k0; k < k0 + 48; ++k)
            p += C[k * NC + i] * C[k * NC + j];
        float (*red)[64] = (float(*)[64])smem_raw;
        red[seg][i] = p;
        __syncthreads();
        if (seg == 0)
            gramP[(size_t)ks * 4096 + i * NC + j] =
                red[0][i] + red[1][i] + red[2][i] + red[3][i];
    } else {
        // U-partial = C^T[kslice] @ W[kslice][128 cols] (verified f32 body)
        int q  = b - 1780;
        int nt = q >> 2, ks = q & 3;
        int n0 = nt * 128, kb = ks * 192;
        float (*Cu)[68]  = (float(*)[68])smem_raw;               // [32][68]
        float (*Wu)[132] = (float(*)[132])(smem_raw + 8704);     // [32][132]
        int tx = tid & 15, ty = tid >> 4;
        float4 a0[4], a1[4];
        #pragma unroll
        for (int i = 0; i < 4; ++i) { a0[i] = make_float4(0,0,0,0); a1[i] = make_float4(0,0,0,0); }
        for (int kc = kb; kc < kb + 192; kc += 32) {
            __syncthreads();
            {   int i4 = tid & 15, kk = tid >> 4;
                *((float4*)&Cu[kk][i4*4])    = *((const float4*)(C + (size_t)(kc+kk)*64 + i4*4));
                *((float4*)&Cu[kk+16][i4*4]) = *((const float4*)(C + (size_t)(kc+kk+16)*64 + i4*4));
            }
            {   int nf = tid & 31, kq2 = tid >> 5;
                #pragma unroll
                for (int u = 0; u < 4; ++u) {
                    int k = kq2 + u * 8;
                    int n = n0 + nf * 4;
                    float4 v = {0.f, 0.f, 0.f, 0.f};
                    if (n < NY) v = *((const float4*)(W + (size_t)(kc + k) * NY + n));
                    *((float4*)&Wu[k][nf*4]) = v;
                }
            }
            __syncthreads();
            #pragma unroll 8
            for (int k = 0; k < 32; ++k) {
                float4 ci = *((float4*)&Cu[k][ty*4]);
                float4 w0 = *((float4*)&Wu[k][tx*8]);
                float4 w1 = *((float4*)&Wu[k][tx*8+4]);
                FMA4(a0[0], ci.x, w0); FMA4(a1[0], ci.x, w1);
                FMA4(a0[1], ci.y, w0); FMA4(a1[1], ci.y, w1);
                FMA4(a0[2], ci.z, w0); FMA4(a1[2], ci.z, w1);
                FMA4(a0[3], ci.w, w0); FMA4(a1[3], ci.w, w1);
            }
        }
        float* Ups = Up + (size_t)ks * 64000;
        #pragma unroll
        for (int i = 0; i < 4; ++i) {
            int irow = ty * 4 + i;
            int n = n0 + tx * 8;
            if (n < NY)     *((float4*)(Ups + (size_t)irow * NY + n))     = a0[i];
            if (n + 4 < NY) *((float4*)(Ups + (size_t)irow * NY + n + 4)) = a1[i];
        }
    }
}

// ===== K2: tmat MFMA (128) || inv (1) || score partials (16) =====
__global__ __launch_bounds__(256) void k_mid(
    const float* __restrict__ X, const uint4* __restrict__ Cb,
    const float* __restrict__ gramP, const float* __restrict__ cmP,
    const float* __restrict__ C, unsigned short* __restrict__ Tb,
    float* __restrict__ ginv, float* __restrict__ SP) {
    __shared__ __align__(16) char smem_raw[52224];
    int b = blockIdx.x, tid = threadIdx.x;
    if (b < 128) {
        // T = X @ C via MFMA, zero LDS (verified R9 body)
        int r0 = b * 64;
        int w  = tid >> 6, l = tid & 63;
        int rowA = r0 + w*16 + (l & 15);
        int kq   = l >> 4;
        const float* xb = X + (size_t)rowA * DD + kq * 8;
        f32x4 acc[4];
        #pragma unroll
        for (int ng = 0; ng < 4; ++ng) acc[ng] = (f32x4){0.f, 0.f, 0.f, 0.f};
        #pragma unroll 2
        for (int ks = 0; ks < 24; ++ks) {
            float4 xa = *((const float4*)(xb + ks*32));
            float4 xc = *((const float4*)(xb + ks*32 + 4));
            B8 a;
            a.u[0] = pk2(xa.x, xa.y); a.u[1] = pk2(xa.z, xa.w);
            a.u[2] = pk2(xc.x, xc.y); a.u[3] = pk2(xc.z, xc.w);
            const uint4* cbase = Cb + (ks*4 + kq)*64 + (l & 15);
            B8 b0, b1, b2, b3;
            b0.q = cbase[0];  b1.q = cbase[16];
            b2.q = cbase[32]; b3.q = cbase[48];
            acc[0] = __builtin_amdgcn_mfma_f32_16x16x32_bf16(a.v, b0.v, acc[0], 0, 0, 0);
            acc[1] = __builtin_amdgcn_mfma_f32_16x16x32_bf16(a.v, b1.v, acc[1], 0, 0, 0);
            acc[2] = __builtin_amdgcn_mfma_f32_16x16x32_bf16(a.v, b2.v, acc[2], 0, 0, 0);
            acc[3] = __builtin_amdgcn_mfma_f32_16x16x32_bf16(a.v, b3.v, acc[3], 0, 0, 0);
        }
        int rw = r0 + w*16 + (l >> 4) * 4;
        #pragma unroll
        for (int ng = 0; ng < 4; ++ng) {
            int n = ng*16 + (l & 15);
            #pragma unroll
            for (int r = 0; r < 4; ++r)
                Tb[(size_t)(rw + r) * 64 + n] = f2bf(acc[ng][r]);
        }
    } else if (b == 128) {
        // register-resident Gauss-Jordan; gram = sum of 4 k-split partials
        int c = tid & 63;
        int q = tid >> 6;
        float a[16], bb[16];
        #pragma unroll
        for (int i = 0; i < 16; ++i) {
            int r = q * 16 + i;
            size_t off = (size_t)r * 64 + c;
            a[i]  = gramP[off] + gramP[4096 + off] + gramP[8192 + off] + gramP[12288 + off];
            bb[i] = (r == c) ? 1.f : 0.f;
        }
        __shared__ float asr[2][64];
        __shared__ float bsr[2][64];
        for (int p = 0; p < 64; ++p) {
            int qp  = p >> 4;
            int lp  = p & 15;
            int par = p & 1;
            if (q == qp) {
                float ap = 0.f, bp = 0.f;
                #pragma unroll
                for (int i = 0; i < 16; ++i)
                    if (i == lp) { ap = a[i]; bp = bb[i]; }
                float App = __shfl(ap, p);
                float s   = 1.0f / App;
                asr[par][c] = ap * s;
                bsr[par][c] = bp * s;
            }
            __syncthreads();
            float as_ = asr[par][c];
            float bs_ = bsr[par][c];
            #pragma unroll
            for (int i = 0; i < 16; ++i) {
                float f = __shfl(a[i], p);
                bool isp = (q == qp) && (i == lp);
                a[i]  = isp ? as_ : fmaf(-f, as_, a[i]);
                bb[i] = isp ? bs_ : fmaf(-f, bs_, bb[i]);
            }
        }
        #pragma unroll
        for (int i = 0; i < 16; ++i)
            ginv[(q * 16 + i) * 64 + c] = bb[i];
    } else {
        // SP-partial = cm[128 rows][192-k slice] @ C; cm = 0.01*sum(4 partials)
        int q = b - 129;
        int tile = q >> 2, ks = q & 3;
        int r0 = tile * 128, kb = ks * 192;
        float (*Mr)[68] = (float(*)[68])smem_raw;                 // [128][68]
        float (*Cs)[68] = (float(*)[68])(smem_raw + 128*68*4);    // [64][68]
        int tx = tid & 15, ty = tid >> 4;
        float4 acc[8];
        #pragma unroll
        for (int r = 0; r < 8; ++r) acc[r] = make_float4(0.f,0.f,0.f,0.f);
        for (int kc = 0; kc < 192; kc += 64) {
            __syncthreads();
            #pragma unroll
            for (int p = 0; p < 8; ++p) {
                int f = tid + p * 256;
                int row = f >> 4, k4 = f & 15;
                int gr = r0 + row;
                int grc = gr < NCL ? gr : (NCL - 1);
                size_t off = (size_t)grc*DD + kb + kc + k4*4;
                float4 c0 = *((const float4*)(cmP + off));
                float4 c1 = *((const float4*)(cmP + 384000 + off));
                float4 c2 = *((const float4*)(cmP + 768000 + off));
                float4 c3 = *((const float4*)(cmP + 1152000 + off));
                float4 m;
                m.x = (c0.x+c1.x+c2.x+c3.x) * 0.01f;
                m.y = (c0.y+c1.y+c2.y+c3.y) * 0.01f;
                m.z = (c0.z+c1.z+c2.z+c3.z) * 0.01f;
                m.w = (c0.w+c1.w+c2.w+c3.w) * 0.01f;
                *((float4*)&Mr[row][k4*4]) = m;
            }
            #pragma unroll
            for (int p = 0; p < 4; ++p) {
                int f = tid + p * 256;
                int k = f >> 4, c4 = f & 15;
                *((float4*)&Cs[k][c4*4]) =
                    *((const float4*)(C + (size_t)(kb+kc+k)*64 + c4*4));
            }
            __syncthreads();
            for (int k0 = 0; k0 < 64; k0 += 4) {
                float4 cv0 = *((float4*)&Cs[k0+0][tx*4]);
                float4 cv1 = *((float4*)&Cs[k0+1][tx*4]);
                float4 cv2 = *((float4*)&Cs[k0+2][tx*4]);
                float4 cv3 = *((float4*)&Cs[k0+3][tx*4]);
                #pragma unroll
                for (int r = 0; r < 8; ++r) {
                    float4 xv = *((float4*)&Mr[ty*8+r][k0]);
                    FMA4(acc[r], xv.x, cv0);
                    FMA4(acc[r], xv.y, cv1);
                    FMA4(acc[r], xv.z, cv2);
                    FMA4(acc[r], xv.w, cv3);
                }
            }
        }
        float* SPs = SP + (size_t)ks * 32000;
        #pragma unroll
        for (int r = 0; r < 8; ++r) {
            int row = r0 + ty * 8 + r;
            if (row < NCL)
                *((float4*)(SPs + (size_t)row * 64 + tx*4)) = acc[r];
        }
    }
}

// ====== K3: Vb = bf16[(Ginv @ sum Up)^T] granules (0..15) || sparse (16) ======
__global__ __launch_bounds__(256) void k_vc(
    const float* __restrict__ ginv, const float* __restrict__ Up,
    float* __restrict__ SP, unsigned short* __restrict__ Vb,
    float* __restrict__ out2) {
    __shared__ __align__(16) char smem_raw[34816];
    int blk = blockIdx.x, tid = threadIdx.x;
    if (blk == 16) {
        // sparse losses (verified body)
        __shared__ float colred[4][64];
        __shared__ float rn[64];
        __shared__ float trc[64];
        __shared__ float r1[4], r2[4];
        const float* SP0 = SP;
        const float* SP1 = SP + 32000;
        const float* SP2 = SP + 64000;
        const float* SP3 = SP + 96000;
        int c = tid & 63, seg = tid >> 6;
        float p = 0.f;
        for (int r = seg; r < NCL; r += 4) {
            int off = r * 64 + c;
            float s = fabsf(SP0[off] + SP1[off] + SP2[off] + SP3[off]);
            SP[off] = s;
            p += s * s;
        }
        colred[seg][c] = p;
        __syncthreads();
        if (seg == 0) {
            float n2  = colred[0][c] + colred[1][c] + colred[2][c] + colred[3][c];
            float inv = 1.0f / fmaxf(sqrtf(n2), EPSN);
            rn[c]  = inv;
            trc[c] = n2 * inv * inv;
        }
        __syncthreads();
        float l1p = 0.f, l2p = 0.f;
        for (int r = tid; r < NCL; r += 256) {
            float rs = 0.f;
            #pragma unroll
            for (int cc = 0; cc < 64; ++cc)
                rs += SP[r * 64 + cc] * rn[cc];
            l1p += rs;
            l2p += rs * rs;
        }
        #pragma unroll
        for (int off = 32; off > 0; off >>= 1) {
            l1p += __shfl_down(l1p, off);
            l2p += __shfl_down(l2p, off);
        }
        int wave = tid >> 6, lane = tid & 63;
        if (lane == 0) { r1[wave] = l1p; r2[wave] = l2p; }
        __syncthreads();
        if (tid == 0) {
            float L1 = r1[0] + r1[1] + r1[2] + r1[3];
            float L2 = r2[0] + r2[1] + r2[2] + r2[3];
            float tr = 0.f;
            #pragma unroll
            for (int cc = 0; cc < 64; ++cc) tr += trc[cc];
            out2[0] = L1;
            out2[1] = L2 - tr;
        }
        return;
    }
    // V = Ginv @ Usum (f32), emitted transposed bf16 (B-fragment layout)
    float (*Us)[68] = (float(*)[68])smem_raw;                     // [64][68]
    float (*Gs)[68] = (float(*)[68])(smem_raw + 64*68*4);         // [64][68]
    int c0 = blk * 64;
    int tx = tid & 15, ty = tid >> 4;
    const float* Up0 = Up;
    const float* Up1 = Up + 64000;
    const float* Up2 = Up + 128000;
    const float* Up3 = Up + 192000;
    #pragma unroll
    for (int p = 0; p < 4; ++p) {
        int f = tid + p * 256;
        int j = f >> 4, n4 = f & 15;
        int n = c0 + n4 * 4;
        float4 v = {0.f, 0.f, 0.f, 0.f};
        if (n < NY) {
            float4 u0 = *((const float4*)(Up0 + (size_t)j * NY + n));
            float4 u1 = *((const float4*)(Up1 + (size_t)j * NY + n));
            float4 u2 = *((const float4*)(Up2 + (size_t)j * NY + n));
            float4 u3 = *((const float4*)(Up3 + (size_t)j * NY + n));
            v.x = u0.x + u1.x + u2.x + u3.x;
            v.y = u0.y + u1.y + u2.y + u3.y;
            v.z = u0.z + u1.z + u2.z + u3.z;
            v.w = u0.w + u1.w + u2.w + u3.w;
        }
        *((float4*)&Us[j][n4*4]) = v;
        *((float4*)&Gs[j][n4*4]) = *((const float4*)(ginv + (size_t)j * 64 + n4*4));
    }
    __syncthreads();
    float4 acc[4];
    #pragma unroll
    for (int i = 0; i < 4; ++i) acc[i] = make_float4(0.f,0.f,0.f,0.f);
    for (int j0 = 0; j0 < 64; j0 += 4) {
        #pragma unroll
        for (int jj = 0; jj < 4; ++jj) {
            float4 g = *((float4*)&Gs[j0+jj][ty*4]);   // Ginv symmetric
            float4 u = *((float4*)&Us[j0+jj][tx*4]);
            FMA4(acc[0], g.x, u);
            FMA4(acc[1], g.y, u);
            FMA4(acc[2], g.z, u);
            FMA4(acc[3], g.w, u);
        }
    }
    #pragma unroll
    for (int i = 0; i < 4; ++i) {
        int krow = ty * 4 + i;
        Vb[(size_t)(c0 + tx*4 + 0) * 64 + krow] = f2bf(acc[i].x);
        Vb[(size_t)(c0 + tx*4 + 1) * 64 + krow] = f2bf(acc[i].y);
        Vb[(size_t)(c0 + tx*4 + 2) * 64 + krow] = f2bf(acc[i].z);
        Vb[(size_t)(c0 + tx*4 + 3) * 64 + krow] = f2bf(acc[i].w);
    }
}

// ============ K4: y = T @ V + b via MFMA, 128x128 tile, zero LDS ============
__global__ __launch_bounds__(256) void k_ypred(
    const uint4* __restrict__ Tb, const uint4* __restrict__ Vbq,
    const float* __restrict__ bh, float* __restrict__ Y) {
    int blk = blockIdx.x, tid = threadIdx.x;
    int rb = blk >> 3, cb = blk & 7;
    int r0g = rb * 128, c0g = cb * 128;
    int w = tid >> 6, l = tid & 63;
    int wr = (w >> 1) * 64, wc = (w & 1) * 64;
    int kq = l >> 4, ln = l & 15;
    f32x4 acc[4][4];
    #pragma unroll
    for (int rg = 0; rg < 4; ++rg)
        #pragma unroll
        for (int ng = 0; ng < 4; ++ng) acc[rg][ng] = (f32x4){0.f,0.f,0.f,0.f};
    #pragma unroll
    for (int ks = 0; ks < 2; ++ks) {
        B8 a[4], bb[4];
        #pragma unroll
        for (int rg = 0; rg < 4; ++rg) {
            int row = r0g + wr + rg*16 + ln;
            a[rg].q = Tb[(size_t)row * 8 + ks*4 + kq];
        }
        #pragma unroll
        for (int ng = 0; ng < 4; ++ng) {
            int n = c0g + wc + ng*16 + ln;
            bb[ng].q = Vbq[(size_t)n * 8 + ks*4 + kq];
        }
        #pragma unroll
        for (int rg = 0; rg < 4; ++rg)
            #pragma unroll
            for (int ng = 0; ng < 4; ++ng)
                acc[rg][ng] = __builtin_amdgcn_mfma_f32_16x16x32_bf16(
                    a[rg].v, bb[ng].v, acc[rg][ng], 0, 0, 0);
    }
    #pragma unroll
    for (int ng = 0; ng < 4; ++ng) {
        int n = c0g + wc + ng*16 + ln;
        if (n < NY) {
            float bias = bh[n];
            #pragma unroll
            for (int rg = 0; rg < 4; ++rg) {
                int row = r0g + wr + rg*16 + kq*4;
                #pragma unroll
                for (int r = 0; r < 4; ++r)
                    Y[(size_t)(row + r) * NY + n] = acc[rg][ng][r] + bias;
            }
        }
    }
}

extern "C" void kernel_launch(void* const* d_in, const int* in_sizes, int n_in,
                              void* d_out, int out_size, void* d_ws, size_t ws_size,
                              hipStream_t stream) {
    const float* X        = (const float*)d_in[0];   // [8192,768]
    const float* clusters = (const float*)d_in[1];   // [500,100,768]
    const float* C        = (const float*)d_in[2];   // [768,64]
    const float* W        = (const float*)d_in[3];   // [768,1000]
    const float* bh       = (const float*)d_in[4];   // [1000]
    float* out = (float*)d_out;                      // y_pred, L1, L2
    float* ws  = (float*)d_ws;

    float* cmP   = ws;                    // 4 x 384000 = 1,536,000
    float* gramP = cmP   + 1536000;       // 4 x 4096 = 16384
    float* ginv  = gramP + 16384;         // 4096
    float* Up    = ginv  + 4096;          // 4 x 64000 = 256000
    float* SP    = Up    + 256000;        // 4 x 32000 = 128000
    float* CbF   = SP    + 128000;        // 24576 floats (Cb granules)
    float* TbF   = CbF   + 24576;         // 262144 floats (Tb bf16)
    float* VbF   = TbF   + 262144;        // 32768 floats (Vb bf16)

    uint4*          Cb  = (uint4*)CbF;
    unsigned short* Tb  = (unsigned short*)TbF;
    unsigned short* Vb  = (unsigned short*)VbF;

    k_front <<<dim3(1812), dim3(256), 0, stream>>>(clusters, C, W, cmP, Cb, gramP, Up);
    k_mid   <<<dim3(145),  dim3(256), 0, stream>>>(X, Cb, gramP, cmP, C, Tb, ginv, SP);
    k_vc    <<<dim3(17),   dim3(256), 0, stream>>>(ginv, Up, SP, Vb, out + (size_t)BS * NY);
    k_ypred <<<dim3(512),  dim3(256), 0, stream>>>((const uint4*)Tb, (const uint4*)Vb, bh, out);
}